// Round 2
// baseline (32.430 us; speedup 1.0000x reference)
//
#include <hip/hip_runtime.h>
#include <math.h>

#define SEQ 30
#define H 64
#define VOCAB 128000

// K_A geometry: 16 lanes per row, 256 threads/block -> 16 rows per iteration.
#define NB 1000
#define ITERS 8               // rows per block = 16 * ITERS = 128; 1000*128 = 128000
#define ROWS_PER_BLOCK (16 * ITERS)

// ws layout (floats): [0..NB) per-block max, [1024..1024+NB) per-block sum
#define WS_M 0
#define WS_S 1024

// ---------------- K_A: redundant GRU + logits + per-block LSE partials ----
__global__ void __launch_bounds__(256) logits_kernel(
        const float* __restrict__ input,
        const float* __restrict__ hidden,
        const float* __restrict__ W_ih,
        const float* __restrict__ W_hh,
        const float* __restrict__ b_ih,
        const float* __restrict__ b_hh,
        const float* __restrict__ W_out,
        const float* __restrict__ b_out,
        float* __restrict__ out,
        float* __restrict__ ws) {
    __shared__ float xs[H], h0s[H], gx[3 * H], gh[3 * H], hnew[H];
    __shared__ float pm[16], ps[16];
    const int t = threadIdx.x;

    // --- GRU, computed redundantly per block (weights are L2/L3-resident) ---
    if (t < H) {
        // softmax over singleton axis => attention weights are all 1.0
        float s = 0.f;
#pragma unroll
        for (int i = 0; i < SEQ; ++i) s += input[i * H + t];
        xs[t] = s;
        h0s[t] = hidden[t];
    }
    __syncthreads();
    if (t < 3 * H) {
        float a = b_ih[t], b = b_hh[t];
        const float4* wi = (const float4*)(W_ih + t * H);
        const float4* wh = (const float4*)(W_hh + t * H);
        const float4* x4 = (const float4*)xs;
        const float4* h4 = (const float4*)h0s;
#pragma unroll
        for (int j = 0; j < H / 4; ++j) {
            const float4 wiv = wi[j], whv = wh[j], xv = x4[j], hv = h4[j];
            a += wiv.x * xv.x + wiv.y * xv.y + wiv.z * xv.z + wiv.w * xv.w;
            b += whv.x * hv.x + whv.y * hv.y + whv.z * hv.z + whv.w * hv.w;
        }
        gx[t] = a;
        gh[t] = b;
    }
    __syncthreads();
    if (t < H) {
        const float r = 1.f / (1.f + expf(-(gx[t] + gh[t])));
        const float z = 1.f / (1.f + expf(-(gx[H + t] + gh[H + t])));
        const float n = tanhf(gx[2 * H + t] + r * gh[2 * H + t]);
        const float hn = (1.f - z) * n + z * h0s[t];
        hnew[t] = hn;
        if (blockIdx.x == 0) out[VOCAB + t] = hn;  // second tuple output
    }
    __syncthreads();

    // --- logits: 16 lanes per row, float4 per lane ---
    const int sub = t & 15;
    const float4 hv = ((const float4*)hnew)[sub];
    const int base = blockIdx.x * ROWS_PER_BLOCK;
    const float4* __restrict__ W4 = (const float4*)W_out;

    float m = -INFINITY, s = 0.f;
#pragma unroll
    for (int it = 0; it < ITERS; ++it) {
        const int row = base + it * 16 + (t >> 4);
        // flat index = base*16 + it*256 + t -> fully sequential across block
        const float4 w = W4[row * 16 + sub];
        float d = w.x * hv.x + w.y * hv.y + w.z * hv.z + w.w * hv.w;
#pragma unroll
        for (int off = 1; off < 16; off <<= 1) d += __shfl_xor(d, off);
        const float logit = d + b_out[row];
        if (sub == 0) {
            out[row] = logit;
            if (logit > m) {
                s = s * expf(m - logit) + 1.f;  // expf(-inf)==0 first iter
                m = logit;
            } else {
                s += expf(logit - m);
            }
        }
    }
    if (sub == 0) { pm[t >> 4] = m; ps[t >> 4] = s; }
    __syncthreads();
    if (t == 0) {
        float M = -INFINITY, S = 0.f;
#pragma unroll
        for (int i = 0; i < 16; ++i) {
            const float m2 = pm[i], s2 = ps[i];
            const float Mn = fmaxf(M, m2);
            S = S * expf(M - Mn) + s2 * expf(m2 - Mn);
            M = Mn;
        }
        ws[WS_M + blockIdx.x] = M;
        ws[WS_S + blockIdx.x] = S;
    }
}

// ---------------- K_B: redundant LSE merge + in-place subtract -------------
__global__ void __launch_bounds__(256) finish_kernel(float* __restrict__ out,
                                                     const float* __restrict__ ws) {
    __shared__ float pm[256], ps[256];
    const int t = threadIdx.x;
    float m = -INFINITY, s = 0.f;
    for (int i = t; i < NB; i += 256) {
        const float m2 = ws[WS_M + i], s2 = ws[WS_S + i];
        const float Mn = fmaxf(m, m2);
        s = s * expf(m - Mn) + s2 * expf(m2 - Mn);
        m = Mn;
    }
    pm[t] = m; ps[t] = s;
    __syncthreads();
    for (int off = 128; off > 0; off >>= 1) {
        if (t < off) {
            const float m2 = pm[t + off], s2 = ps[t + off];
            const float Mn = fmaxf(pm[t], m2);
            ps[t] = ps[t] * expf(pm[t] - Mn) + s2 * expf(m2 - Mn);
            pm[t] = Mn;
        }
        __syncthreads();
    }
    const float lse = pm[0] + logf(ps[0]);

    // exactly one float4 per thread: 125 blocks * 256 threads = 32000 float4
    const int i = blockIdx.x * 256 + t;
    float4* o4 = (float4*)out;
    float4 v = o4[i];
    v.x -= lse; v.y -= lse; v.z -= lse; v.w -= lse;
    o4[i] = v;
}

extern "C" void kernel_launch(void* const* d_in, const int* in_sizes, int n_in,
                              void* d_out, int out_size, void* d_ws, size_t ws_size,
                              hipStream_t stream) {
    const float* input  = (const float*)d_in[0];
    const float* hidden = (const float*)d_in[1];
    // d_in[2] = W_attn, d_in[3] = b_attn: dead (softmax over singleton axis)
    const float* W_ih   = (const float*)d_in[4];
    const float* W_hh   = (const float*)d_in[5];
    const float* b_ih   = (const float*)d_in[6];
    const float* b_hh   = (const float*)d_in[7];
    const float* W_out  = (const float*)d_in[8];
    const float* b_out  = (const float*)d_in[9];
    // d_in[10] = time_step: unused
    float* out = (float*)d_out;
    float* ws  = (float*)d_ws;

    logits_kernel<<<NB, 256, 0, stream>>>(input, hidden, W_ih, W_hh, b_ih, b_hh,
                                          W_out, b_out, out, ws);
    finish_kernel<<<VOCAB / 4 / 256, 256, 0, stream>>>(out, ws);
}